// Round 9
// baseline (142.096 us; speedup 1.0000x reference)
//
#include <hip/hip_runtime.h>
#include <math.h>

#define BATCH  512
#define NROWS  256
#define NVECS  8
#define VSIZE  128
#define DIM    1024   // NVECS*VSIZE
#define NCOMBO 256

// ---------------------------------------------------------------------------
// R9 = R7 (DPP reductions, 140.6us verified) with a 2x b-tile to amortize
// the per-block prologue. Tile = 16 b x 8 r, 512 threads (8 waves),
// grid 32x32 = 1024 blocks (was 8b x 8r / 256 thr / 2048 blocks).
//
// Why: R8 showed the r-loop is overlap-absorbed (removing 25% of its work
// was null-negative); the critical path is {stage 33KB + barrier} x 2048
// blocks + the store stream. Doubling b per block halves staging events,
// staging traffic (67 -> 34 MB) and barriers per unit of output, with
// per-wave structure identical to R7 (2 b-rows/wave, 32 Q VGPRs, same
// r-loop, same store pattern). Occupancy unchanged in waves/CU (VGPR-capped
// at 16 either way).
// ---------------------------------------------------------------------------

// sum over each 8-lane group, result in all 8 lanes (pure VALU, R7-verified)
__device__ __forceinline__ float dpp8_sum(float x) {
  int v;
  v = __builtin_amdgcn_update_dpp(0, __float_as_int(x), 0xB1, 0xF, 0xF, true);
  x += __int_as_float(v);                       // + lane^1  (quad_perm 1,0,3,2)
  v = __builtin_amdgcn_update_dpp(0, __float_as_int(x), 0x4E, 0xF, 0xF, true);
  x += __int_as_float(v);                       // + lane^2  (quad_perm 2,3,0,1)
  v = __builtin_amdgcn_update_dpp(0, __float_as_int(x), 0x141, 0xF, 0xF, true);
  x += __int_as_float(v);                       // + other quad (row_half_mirror)
  return x;
}

__global__ __launch_bounds__(512) void fused_kernel(
    const float* __restrict__ q, const float* __restrict__ w,
    float* __restrict__ out) {
  __shared__ __align__(16) float Ws[8 * 1056];  // 33 KB: 8 rows, 8x(128+4)
  const int t    = threadIdx.x;                 // 0..511
  const int wv   = t >> 6, lane = t & 63;       // wv 0..7
  const int bs   = blockIdx.x * 16, rs = blockIdx.y * 8;
  const int n    = lane >> 3, c = lane & 7;
  const int koff = n * VSIZE + c * 16;
  const int b0   = bs + 2 * wv;                 // 2 b-rows per wave

  // stage W tile (8 x 1024 floats): 512 threads -> 4 iters, consecutive 16B
  #pragma unroll
  for (int i = 0; i < 4; ++i) {
    int f = i * 512 + t;        // float4 index 0..2047
    int g = f << 2;             // element index
    int row = g >> 10, e = g & 1023;
    float4 v = *(const float4*)(w + (size_t)(rs + row) * DIM + e);
    *(float4*)(Ws + row * 1056 + (e >> 7) * 132 + (e & 127)) = v;
  }

  // Q rows -> registers; inline sub-vector inverse norms via DPP reduce.
  float4 qa[4], qb[4];
  float qs0 = 0.f, qs1 = 0.f;
  {
    const float* Q0 = q + (size_t)b0 * DIM + koff;
    #pragma unroll
    for (int j = 0; j < 4; ++j) {
      qa[j] = *(const float4*)(Q0 + 4 * j);
      qb[j] = *(const float4*)(Q0 + DIM + 4 * j);
      qs0 = fmaf(qa[j].x, qa[j].x, qs0); qs0 = fmaf(qa[j].y, qa[j].y, qs0);
      qs0 = fmaf(qa[j].z, qa[j].z, qs0); qs0 = fmaf(qa[j].w, qa[j].w, qs0);
      qs1 = fmaf(qb[j].x, qb[j].x, qs1); qs1 = fmaf(qb[j].y, qb[j].y, qs1);
      qs1 = fmaf(qb[j].z, qb[j].z, qs1); qs1 = fmaf(qb[j].w, qb[j].w, qs1);
    }
  }
  qs0 = dpp8_sum(qs0);
  qs1 = dpp8_sum(qs1);
  const float iq0 = 1.0f / fmaxf(sqrtf(qs0), 1e-8f);
  const float iq1 = 1.0f / fmaxf(sqrtf(qs1), 1e-8f);

  __syncthreads();

  const float* Wb = Ws + n * 132 + c * 16;
  float* out0 = out + ((size_t)b0 * NROWS + rs) * NCOMBO + lane * 4;

  #pragma unroll 2
  for (int r = 0; r < 8; ++r) {
    // --- dots + w-norm for row rs+r (W from LDS) ---
    const float* Wr = Wb + r * 1056;
    float s0 = 0.f, s1 = 0.f, wss = 0.f;
    #pragma unroll
    for (int j = 0; j < 4; ++j) {
      float4 w4 = *(const float4*)(Wr + 4 * j);
      s0 = fmaf(qa[j].x, w4.x, s0); s0 = fmaf(qa[j].y, w4.y, s0);
      s0 = fmaf(qa[j].z, w4.z, s0); s0 = fmaf(qa[j].w, w4.w, s0);
      s1 = fmaf(qb[j].x, w4.x, s1); s1 = fmaf(qb[j].y, w4.y, s1);
      s1 = fmaf(qb[j].z, w4.z, s1); s1 = fmaf(qb[j].w, w4.w, s1);
      wss = fmaf(w4.x, w4.x, wss); wss = fmaf(w4.y, w4.y, wss);
      wss = fmaf(w4.z, w4.z, wss); wss = fmaf(w4.w, w4.w, wss);
    }
    s0  = dpp8_sum(s0);
    s1  = dpp8_sum(s1);
    wss = dpp8_sum(wss);
    const float iw  = 1.0f / fmaxf(sqrtf(wss), 1e-8f);
    const float cs0 = fmaxf(s0 * iq0 * iw, 0.f);
    const float cs1 = fmaxf(s1 * iq1 * iw, 0.f);

    // broadcast cs[n] from lane 8n to all lanes (uniform index -> readlane)
    float v0[8], v1[8];
    #pragma unroll
    for (int j = 0; j < 8; ++j) {
      v0[j] = __shfl(cs0, j * 8, 64);
      v1[j] = __shfl(cs1, j * 8, 64);
    }

    // --- expand + store both b-rows for this r (stores spread over loop) ---
    #pragma unroll
    for (int pp = 0; pp < 2; ++pp) {
      const float* v = pp ? v1 : v0;
      float t2 = (lane & 1)  ? 1.f - v[2] : v[2];
      float t3 = (lane & 2)  ? 1.f - v[3] : v[3];
      float t4 = (lane & 4)  ? 1.f - v[4] : v[4];
      float t5 = (lane & 8)  ? 1.f - v[5] : v[5];
      float t6 = (lane & 16) ? 1.f - v[6] : v[6];
      float t7 = (lane & 32) ? 1.f - v[7] : v[7];
      float base = ((t2 * t3) * (t4 * t5)) * (t6 * t7);
      float c0 = v[0], c1 = v[1];
      float4 o;
      o.x = base * (c0 * c1);
      o.y = base * ((1.f - c0) * c1);
      o.z = base * (c0 * (1.f - c1));
      o.w = base * ((1.f - c0) * (1.f - c1));
      *(float4*)(out0 + ((size_t)pp * NROWS + r) * NCOMBO) = o;
    }
  }
}

// ---------------------------------------------------------------------------
extern "C" void kernel_launch(void* const* d_in, const int* in_sizes, int n_in,
                              void* d_out, int out_size, void* d_ws, size_t ws_size,
                              hipStream_t stream) {
  const float* query  = (const float*)d_in[0];   // [512][1024]
  const float* weight = (const float*)d_in[1];   // [256][1024]
  float* out = (float*)d_out;                    // [512][256][256]
  (void)d_ws; (void)ws_size;

  hipLaunchKernelGGL(fused_kernel, dim3(32, 32), dim3(512), 0, stream,
                     query, weight, out);
}